// Round 3
// baseline (535.406 us; speedup 1.0000x reference)
//
#include <hip/hip_runtime.h>
#include <stdint.h>

// AnyprecisionLinear: out[s,o] = sum_k x[s,k] * lut[o, code(o,k)>>4]
// M=2048, N=8192, K=8192. fp32 in/out, bf16 MFMA compute.
//
// R6 changes vs R5 (gemm_bt only):
//  - Operand double-buffering (afA/afB, bqA/bqB): each phase's ds_reads are
//    the NEXT phase's fragments, issued at phase start and drained under the
//    current phase's 16 MFMAs. This is the m201 mechanism R5 lacked (R5's
//    reads fed the SAME phase -> barrier-locked serial LDS/MFMA alternation:
//    2484 MFMA + 2688 LDS ~= 5494 cy/K-tile measured).
//  - Quadrant order (0,0),(0,1),(1,0),(1,1); reads: P1 bqB(t), P2 afB(t),
//    P3 afA(t+1) [other buf], P4 bqA(t+1). 24 reads/wave/tile (bq reload
//    eliminated). Barriers 8 -> 4 per tile.
//  - Stages all target tile t+2's buffer, placed directly after each LDS
//    region's last read + fence: P1 A q0,q2; P2 B q0,q1; P3 A q1,q3;
//    P4 B q2,q3. lgkmcnt(0) at P2-end/P4-end are the exact WAR fences.
//    vmcnt(8) once per tile at P4-end (drained loads are 4-7 phases old).

#define M_DIM 2048
#define N_DIM 8192
#define K_DIM 8192
#define BM 256
#define BN 256
#define BK 64
#define KT (K_DIM / BK)  // 128 K-tiles

typedef __bf16 bf16x8 __attribute__((ext_vector_type(8)));
typedef float f32x4 __attribute__((ext_vector_type(4)));

__device__ __forceinline__ unsigned int f2bf(float f) {
  // round-to-nearest-even fp32 -> bf16
  unsigned int u = __float_as_uint(f);
  return (u + 0x7FFFu + ((u >> 16) & 1u)) >> 16;
}

// ---------------- dequant: qweight (int32-packed 8-bit codes) -> bf16 W ----
__global__ __launch_bounds__(256) void dequant_kernel(
    const int4* __restrict__ qw4,
    const float* __restrict__ lut,
    unsigned short* __restrict__ wb) {
  __shared__ unsigned int slut[4 * 16 * 64];  // 16 KB
  const int wave = threadIdx.x >> 6;
  const int lane = threadIdx.x & 63;
  const int row = (blockIdx.x << 2) + wave;

  unsigned int* tbl = slut + wave * (16 * 64) + lane;  // this lane's column
  const float* lr = lut + row * 16;
#pragma unroll
  for (int e = 0; e < 16; ++e) tbl[e * 64] = f2bf(lr[e]);

  const int4* src = qw4 + (size_t)row * 512 + lane;  // 512 int4/row
  unsigned short* dst = wb + (size_t)row * K_DIM + lane * 16;

#pragma unroll
  for (int it = 0; it < 8; ++it) {
    int4 q = src[it * 64];
    unsigned int w[4] = {(unsigned int)q.x, (unsigned int)q.y,
                         (unsigned int)q.z, (unsigned int)q.w};
    unsigned int v[16];
#pragma unroll
    for (int j = 0; j < 4; ++j) {
#pragma unroll
      for (int k = 0; k < 4; ++k)
        v[j * 4 + k] = tbl[((w[j] >> (8 * k + 4)) & 15u) * 64];
    }
    uint4 o0, o1;
    o0.x = v[0] | (v[1] << 16);   o0.y = v[2]  | (v[3] << 16);
    o0.z = v[4] | (v[5] << 16);   o0.w = v[6]  | (v[7] << 16);
    o1.x = v[8] | (v[9] << 16);   o1.y = v[10] | (v[11] << 16);
    o1.z = v[12] | (v[13] << 16); o1.w = v[14] | (v[15] << 16);
    uint4* dp = (uint4*)(dst + it * 1024);
    dp[0] = o0;
    dp[1] = o1;
  }
}

// ---------------- x fp32 -> bf16, 8 elements/thread, 16 B stores -----------
__global__ __launch_bounds__(256) void cvt_x_kernel(
    const float4* __restrict__ x4, unsigned int* __restrict__ xb) {
  const int idx = blockIdx.x * 256 + threadIdx.x;
  float4 a = x4[2 * idx];
  float4 b = x4[2 * idx + 1];
  uint4 o;
  o.x = f2bf(a.x) | (f2bf(a.y) << 16);
  o.y = f2bf(a.z) | (f2bf(a.w) << 16);
  o.z = f2bf(b.x) | (f2bf(b.y) << 16);
  o.w = f2bf(b.z) | (f2bf(b.w) << 16);
  ((uint4*)xb)[idx] = o;
}

// ---------------- GEMM: C = A * B^T, 256x256x64 tiles ----------------------
// LDS per buffer: [256 rows][64 cols] bf16; 16 B chunk-slot s of row r holds
// global k-chunk s ^ (r&7). Conflict-free for the 16x16x32 reader (R4/R5: 0).
// A/B operand (16x16x32): row/col = lane&15, k = (lane>>4)*8 + j.
// C/D: col = lane&15, row = (lane>>4)*4 + reg  [m89/m91].

__device__ __forceinline__ void stage_q(const unsigned short* __restrict__ g,
                                        unsigned short* lds_tile, int grow0,
                                        int qrow, int koff, int wave, int srow,
                                        int scol) {
  const unsigned short* src =
      g + (size_t)(grow0 + qrow + (wave << 3) + srow) * K_DIM + koff + scol;
  __builtin_amdgcn_global_load_lds(
      (const __attribute__((address_space(1))) void*)src,
      (__attribute__((address_space(3))) void*)(lds_tile +
                                                (qrow + (wave << 3)) * BK),
      16, 0, 0);
}

// aoff0/aoff1: per-lane LDS element offsets (shared by A and B reads):
//   aoffK = rrow*BK + ((K*4+rk)^(rrow&7))*8
__device__ __forceinline__ void load_a4(const unsigned short* __restrict__ s,
                                        int row0, int aoff0, int aoff1,
                                        bf16x8 out[4][2]) {
#pragma unroll
  for (int mi = 0; mi < 4; ++mi) {
    out[mi][0] = *(const bf16x8*)(s + (row0 + mi * 16) * BK + aoff0);
    out[mi][1] = *(const bf16x8*)(s + (row0 + mi * 16) * BK + aoff1);
  }
}

__device__ __forceinline__ void load_b2(const unsigned short* __restrict__ s,
                                        int row0, int aoff0, int aoff1,
                                        bf16x8 out[2][2]) {
#pragma unroll
  for (int nj = 0; nj < 2; ++nj) {
    out[nj][0] = *(const bf16x8*)(s + (row0 + nj * 16) * BK + aoff0);
    out[nj][1] = *(const bf16x8*)(s + (row0 + nj * 16) * BK + aoff1);
  }
}

// 16 MFMAs of one quadrant (4 m-frags x 2 n-frags x K=64).
#define MFMA_Q(AF, BQ, MH, NH)                                                \
  _Pragma("unroll")                                                           \
  for (int ks = 0; ks < 2; ++ks)                                              \
    _Pragma("unroll")                                                         \
    for (int mi = 0; mi < 4; ++mi)                                            \
      _Pragma("unroll")                                                       \
      for (int nj = 0; nj < 2; ++nj)                                          \
        acc[(MH)*4 + mi][(NH)*2 + nj] =                                       \
            __builtin_amdgcn_mfma_f32_16x16x32_bf16(                          \
                AF[mi][ks], BQ[nj][ks], acc[(MH)*4 + mi][(NH)*2 + nj],        \
                0, 0, 0);

#define SBAR asm volatile("s_barrier" ::: "memory")

// One K-tile = 4 phases. Register fragment lifetimes (loaded 1 phase early):
//   afA(t): loaded t-1.P3, used t.P1,P2   afB(t): loaded t.P2, used t.P3,P4
//   bqA(t): loaded t-1.P4, used t.P1,P3   bqB(t): loaded t.P1, used t.P2,P4
// LDS region last-reads of buffer BF (tile t data):
//   A q0,q2 (mh0): t-1.P3   A q1,q3 (mh1): t.P2
//   B q0,q1 (nh0): t-1.P4   B q2,q3 (nh1): t.P1
// Stages (tile t+2 -> BF) placed after last read + >=1 fence+barrier:
//   P1: A q0,q2   P2: B q0,q1   P3: A q1,q3   P4: B q2,q3
// Fences: lgkmcnt(0) at P2-end (afB reads vs P3's A-stage) and P4-end
// (afA/bqA cross-tile reads vs t+1.P1/P2's stages). vmcnt(8) at P4-end:
// outstanding = t-1.P3,P4 (4) + t.P1-P4 (8) + ... = 16 -> drains the 8
// oldest (ages 4-7 phases, HBM latency fully hidden), keeps t's 8 in flight.
#define KTILE(T, BF)                                                          \
  {                                                                           \
    const int ko2 = (((T) + 2) & (KT - 1)) * BK;                              \
    const unsigned short* sa_ = sA[BF];                                       \
    const unsigned short* sb_ = sB[BF];                                       \
    const unsigned short* sa1 = sA[(BF) ^ 1];                                 \
    const unsigned short* sb1 = sB[(BF) ^ 1];                                 \
    unsigned short* wa = sA[BF];                                              \
    unsigned short* wbuf = sB[BF];                                            \
    /* P1 (0,0): prefetch bqB(t); stage A q0,q2 (t+2) */                      \
    load_b2(sb_, bnlo + 128, aoff0, aoff1, bqB);                              \
    stage_q(A, wa, m0, 0, ko2, wave, srow, scol);                             \
    stage_q(A, wa, m0, 128, ko2, wave, srow, scol);                           \
    __builtin_amdgcn_s_setprio(1);                                            \
    MFMA_Q(afA, bqA, 0, 0);                                                   \
    __builtin_amdgcn_s_setprio(0);                                            \
    SBAR;                                                                     \
    /* P2 (0,1): prefetch afB(t); stage B q0,q1 (t+2) */                      \
    load_a4(sa_, wm + 64, aoff0, aoff1, afB);                                 \
    stage_q(B, wbuf, n0, 0, ko2, wave, srow, scol);                           \
    stage_q(B, wbuf, n0, 64, ko2, wave, srow, scol);                          \
    __builtin_amdgcn_s_setprio(1);                                            \
    MFMA_Q(afA, bqB, 0, 1);                                                   \
    __builtin_amdgcn_s_setprio(0);                                            \
    asm volatile("s_waitcnt lgkmcnt(0)" ::: "memory");                        \
    SBAR;                                                                     \
    /* P3 (1,0): prefetch afA(t+1) from other buf; stage A q1,q3 (t+2) */     \
    load_a4(sa1, wm + 0, aoff0, aoff1, afA);                                  \
    stage_q(A, wa, m0, 64, ko2, wave, srow, scol);                            \
    stage_q(A, wa, m0, 192, ko2, wave, srow, scol);                           \
    __builtin_amdgcn_s_setprio(1);                                            \
    MFMA_Q(afB, bqA, 1, 0);                                                   \
    __builtin_amdgcn_s_setprio(0);                                            \
    SBAR;                                                                     \
    /* P4 (1,1): prefetch bqA(t+1) from other buf; stage B q2,q3 (t+2) */     \
    load_b2(sb1, bnlo, aoff0, aoff1, bqA);                                    \
    stage_q(B, wbuf, n0, 128, ko2, wave, srow, scol);                         \
    stage_q(B, wbuf, n0, 192, ko2, wave, srow, scol);                         \
    __builtin_amdgcn_s_setprio(1);                                            \
    MFMA_Q(afB, bqB, 1, 1);                                                   \
    __builtin_amdgcn_s_setprio(0);                                            \
    asm volatile("s_waitcnt lgkmcnt(0)" ::: "memory");                        \
    asm volatile("s_waitcnt vmcnt(8)" ::: "memory");                          \
    SBAR;                                                                     \
  }

__global__ __launch_bounds__(512, 2) void gemm_bt(
    const unsigned short* __restrict__ A,
    const unsigned short* __restrict__ B,
    float* __restrict__ C) {
  __shared__ __align__(16) unsigned short sA[2][BM * BK];  // 64 KB
  __shared__ __align__(16) unsigned short sB[2][BN * BK];  // 64 KB

  const int tid = threadIdx.x;
  const int wave = tid >> 6;
  const int lane = tid & 63;

  // XCD swizzle: 256 blocks; XCD c owns m-tile c, n-tiles 0..31 -> the 4 MB
  // A panel is resident in that XCD's L2.
  const int bid = blockIdx.x;
  const int swz = (bid & 7) * 32 + (bid >> 3);
  const int m0 = (swz >> 5) * BM;
  const int n0 = (swz & 31) * BN;

  const int wm = (wave >> 2) * 128;  // 0 or 128 (M-half)
  const int bnlo = (wave & 3) * 32;  // B row base for nh=0 (nh=1: +128)

  // staging lane coords
  const int srow = lane >> 3;                // 0..7
  const int scol = ((lane & 7) ^ srow) * 8;  // swizzled k-chunk (elements)

  // reader lane coords -> shared per-lane LDS element offsets
  const int rrow = lane & 15;
  const int rk = lane >> 4;  // 0..3
  const int aoff0 = rrow * BK + ((rk) ^ (rrow & 7)) * 8;
  const int aoff1 = rrow * BK + ((4 + rk) ^ (rrow & 7)) * 8;

  bf16x8 afA[4][2], afB[4][2];
  bf16x8 bqA[2][2], bqB[2][2];
  f32x4 acc[8][4];
#pragma unroll
  for (int m = 0; m < 8; ++m)
#pragma unroll
    for (int n = 0; n < 4; ++n)
#pragma unroll
      for (int r = 0; r < 4; ++r) acc[m][n][r] = 0.0f;

  // Prologue: stage tile 0 (8 loads, buf0) then tile 1 (8 loads, buf1);
  // vmcnt(8) -> tile 0 landed; read afA(t0), bqA(t0); fence before the loop
  // (t0.P1 stages A q0,q2(t2) over the region afA just read).
  stage_q(A, sA[0], m0, 0, 0, wave, srow, scol);
  stage_q(A, sA[0], m0, 64, 0, wave, srow, scol);
  stage_q(A, sA[0], m0, 128, 0, wave, srow, scol);
  stage_q(A, sA[0], m0, 192, 0, wave, srow, scol);
  stage_q(B, sB[0], n0, 0, 0, wave, srow, scol);
  stage_q(B, sB[0], n0, 64, 0, wave, srow, scol);
  stage_q(B, sB[0], n0, 128, 0, wave, srow, scol);
  stage_q(B, sB[0], n0, 192, 0, wave, srow, scol);
  stage_q(A, sA[1], m0, 0, BK, wave, srow, scol);
  stage_q(A, sA[1], m0, 64, BK, wave, srow, scol);
  stage_q(A, sA[1], m0, 128, BK, wave, srow, scol);
  stage_q(A, sA[1], m0, 192, BK, wave, srow, scol);
  stage_q(B, sB[1], n0, 0, BK, wave, srow, scol);
  stage_q(B, sB[1], n0, 64, BK, wave, srow, scol);
  stage_q(B, sB[1], n0, 128, BK, wave, srow, scol);
  stage_q(B, sB[1], n0, 192, BK, wave, srow, scol);
  asm volatile("s_waitcnt vmcnt(8)" ::: "memory");
  SBAR;
  load_a4(sA[0], wm + 0, aoff0, aoff1, afA);
  load_b2(sB[0], bnlo, aoff0, aoff1, bqA);
  asm volatile("s_waitcnt lgkmcnt(0)" ::: "memory");
  SBAR;

#pragma unroll 1
  for (int tt = 0; tt < KT / 2; ++tt) {
    KTILE(2 * tt, 0)
    KTILE(2 * tt + 1, 1)
  }
  asm volatile("s_waitcnt vmcnt(0) lgkmcnt(0)" ::: "memory");

  // Epilogue: C/D layout col = lane&15, row = (lane>>4)*4 + reg.
  // Row for acc[m][.]: wm + m*16. Col for acc[.][n]: bnlo + (n>>1)*128 +
  // (n&1)*16.
  const int crow0 = m0 + wm + 4 * rk;
  const int ccol0 = n0 + bnlo + rrow;
#pragma unroll
  for (int m = 0; m < 8; ++m)
#pragma unroll
    for (int n = 0; n < 4; ++n)
#pragma unroll
      for (int r = 0; r < 4; ++r)
        C[(size_t)(crow0 + m * 16 + r) * N_DIM + ccol0 + (n >> 1) * 128 +
          (n & 1) * 16] = acc[m][n][r];
}

// Safety-net fallback (only if ws_size < 160 MB): correct fp32, slow.
__global__ void naive_kernel(const float* __restrict__ x,
                             const int* __restrict__ qw,
                             const float* __restrict__ lut,
                             float* __restrict__ out) {
  int o = blockIdx.x * blockDim.x + threadIdx.x;
  int s = blockIdx.y;
  const float* xr = x + (size_t)s * K_DIM;
  const unsigned int* qr = (const unsigned int*)qw + (size_t)o * (K_DIM / 4);
  const float* l = lut + o * 16;
  float acc = 0.f;
  for (int w = 0; w < K_DIM / 4; ++w) {
    unsigned int q = qr[w];
    acc += xr[w * 4 + 0] * l[(q >> 4) & 15u]
         + xr[w * 4 + 1] * l[(q >> 12) & 15u]
         + xr[w * 4 + 2] * l[(q >> 20) & 15u]
         + xr[w * 4 + 3] * l[(q >> 28) & 15u];
  }
  out[(size_t)s * N_DIM + o] = acc;
}

extern "C" void kernel_launch(void* const* d_in, const int* in_sizes, int n_in,
                              void* d_out, int out_size, void* d_ws,
                              size_t ws_size, hipStream_t stream) {
  const float* x = (const float*)d_in[0];
  const int* qw = (const int*)d_in[1];
  const float* lut = (const float*)d_in[2];
  float* out = (float*)d_out;

  const size_t wb_elems = (size_t)N_DIM * K_DIM;  // 128 MB bf16
  const size_t xb_elems = (size_t)M_DIM * K_DIM;  //  32 MB bf16
  const size_t need = (wb_elems + xb_elems) * sizeof(unsigned short);

  if (ws_size >= need) {
    unsigned short* wb = (unsigned short*)d_ws;
    unsigned short* xb = wb + wb_elems;

    hipLaunchKernelGGL(dequant_kernel, dim3(N_DIM / 4), dim3(256), 0, stream,
                       (const int4*)qw, lut, wb);

    const int n_thr = M_DIM * K_DIM / 8;  // 8 elem/thread
    hipLaunchKernelGGL(cvt_x_kernel, dim3(n_thr / 256), dim3(256), 0, stream,
                       (const float4*)x, (unsigned int*)xb);

    hipLaunchKernelGGL(gemm_bt, dim3((M_DIM / BM) * (N_DIM / BN)), dim3(512),
                       0, stream, xb, wb, out);
  } else {
    dim3 grid(N_DIM / 256, M_DIM);
    hipLaunchKernelGGL(naive_kernel, grid, dim3(256), 0, stream, x, qw, lut,
                       out);
  }
}

// Round 4
// 461.736 us; speedup vs baseline: 1.1596x; 1.1596x over previous
//
#include <hip/hip_runtime.h>
#include <stdint.h>

// AnyprecisionLinear: out[s,o] = sum_k x[s,k] * lut[o, code(o,k)>>4]
// M=2048, N=8192, K=8192. fp32 in/out, bf16 MFMA compute.
//
// R7 changes vs R6 (gemm_bt only):
//  - R6 regressed (370 us, MfmaUtil 31.6%) from (a) scratch spill: VGPR hit
//    the 128 arch cap (WRITE_SIZE +6.6 MB), (b) compiler free to sink the
//    prefetch ds_reads to phase end / hoist MFMA (no sched pins).
//  - Fix a: staging addresses split into loop-invariant per-lane offset
//    (1 VGPR) + SGPR-arithmetic uniform part -> no per-call 64-bit VALU
//    address recompute, ~15-20 fewer arch VGPRs.
//  - Fix b: __builtin_amdgcn_sched_barrier(0) fencing {reads,stages} from
//    the MFMA cluster in every phase (loads pinned at phase start, MFMA
//    pinned inside the phase).
//  - Fix c (latent race in R5/R6): cross-buffer fragment prefetches (afA/bqA
//    of tile t+1 at P3/P4) now covered by staggered vmcnt guards 10/8/6 at
//    P3-begin/P4-begin/P4-end. Verified by outstanding-count tracking:
//    steady-state entry = 6 outstanding (S(t-1) p3-8); every drained load is
//    >=3 phases old -> guards cost nothing; every read is provably landed.

#define M_DIM 2048
#define N_DIM 8192
#define K_DIM 8192
#define BM 256
#define BN 256
#define BK 64
#define KT (K_DIM / BK)  // 128 K-tiles

typedef __bf16 bf16x8 __attribute__((ext_vector_type(8)));
typedef float f32x4 __attribute__((ext_vector_type(4)));

__device__ __forceinline__ unsigned int f2bf(float f) {
  // round-to-nearest-even fp32 -> bf16
  unsigned int u = __float_as_uint(f);
  return (u + 0x7FFFu + ((u >> 16) & 1u)) >> 16;
}

// ---------------- dequant: qweight (int32-packed 8-bit codes) -> bf16 W ----
__global__ __launch_bounds__(256) void dequant_kernel(
    const int4* __restrict__ qw4,
    const float* __restrict__ lut,
    unsigned short* __restrict__ wb) {
  __shared__ unsigned int slut[4 * 16 * 64];  // 16 KB
  const int wave = threadIdx.x >> 6;
  const int lane = threadIdx.x & 63;
  const int row = (blockIdx.x << 2) + wave;

  unsigned int* tbl = slut + wave * (16 * 64) + lane;  // this lane's column
  const float* lr = lut + row * 16;
#pragma unroll
  for (int e = 0; e < 16; ++e) tbl[e * 64] = f2bf(lr[e]);

  const int4* src = qw4 + (size_t)row * 512 + lane;  // 512 int4/row
  unsigned short* dst = wb + (size_t)row * K_DIM + lane * 16;

#pragma unroll
  for (int it = 0; it < 8; ++it) {
    int4 q = src[it * 64];
    unsigned int w[4] = {(unsigned int)q.x, (unsigned int)q.y,
                         (unsigned int)q.z, (unsigned int)q.w};
    unsigned int v[16];
#pragma unroll
    for (int j = 0; j < 4; ++j) {
#pragma unroll
      for (int k = 0; k < 4; ++k)
        v[j * 4 + k] = tbl[((w[j] >> (8 * k + 4)) & 15u) * 64];
    }
    uint4 o0, o1;
    o0.x = v[0] | (v[1] << 16);   o0.y = v[2]  | (v[3] << 16);
    o0.z = v[4] | (v[5] << 16);   o0.w = v[6]  | (v[7] << 16);
    o1.x = v[8] | (v[9] << 16);   o1.y = v[10] | (v[11] << 16);
    o1.z = v[12] | (v[13] << 16); o1.w = v[14] | (v[15] << 16);
    uint4* dp = (uint4*)(dst + it * 1024);
    dp[0] = o0;
    dp[1] = o1;
  }
}

// ---------------- x fp32 -> bf16, 8 elements/thread, 16 B stores -----------
__global__ __launch_bounds__(256) void cvt_x_kernel(
    const float4* __restrict__ x4, unsigned int* __restrict__ xb) {
  const int idx = blockIdx.x * 256 + threadIdx.x;
  float4 a = x4[2 * idx];
  float4 b = x4[2 * idx + 1];
  uint4 o;
  o.x = f2bf(a.x) | (f2bf(a.y) << 16);
  o.y = f2bf(a.z) | (f2bf(a.w) << 16);
  o.z = f2bf(b.x) | (f2bf(b.y) << 16);
  o.w = f2bf(b.z) | (f2bf(b.w) << 16);
  ((uint4*)xb)[idx] = o;
}

// ---------------- GEMM: C = A * B^T, 256x256x64 tiles ----------------------
// LDS per buffer: [256 rows][64 cols] bf16; 16 B chunk-slot s of row r holds
// global k-chunk s ^ (r&7). Conflict-free for the 16x16x32 reader.
// A/B operand (16x16x32): row/col = lane&15, k = (lane>>4)*8 + j.
// C/D: col = lane&15, row = (lane>>4)*4 + reg  [m89/m91].

// off: 32-bit element offset = uniform(row-base*K + koff) + per-lane(laneoff).
// lds must be wave-uniform; HW adds lane*16 bytes.
__device__ __forceinline__ void stage2(const unsigned short* __restrict__ g,
                                       unsigned short* lds, unsigned off) {
  __builtin_amdgcn_global_load_lds(
      (const __attribute__((address_space(1))) void*)(g + off),
      (__attribute__((address_space(3))) void*)lds, 16, 0, 0);
}

// aoffK = rrow*BK + ((K*4+rk)^(rrow&7))*8  (per-lane, shared by A and B)
__device__ __forceinline__ void load_a4(const unsigned short* __restrict__ s,
                                        int row0, int aoff0, int aoff1,
                                        bf16x8 out[4][2]) {
#pragma unroll
  for (int mi = 0; mi < 4; ++mi) {
    out[mi][0] = *(const bf16x8*)(s + (row0 + mi * 16) * BK + aoff0);
    out[mi][1] = *(const bf16x8*)(s + (row0 + mi * 16) * BK + aoff1);
  }
}

__device__ __forceinline__ void load_b2(const unsigned short* __restrict__ s,
                                        int row0, int aoff0, int aoff1,
                                        bf16x8 out[2][2]) {
#pragma unroll
  for (int nj = 0; nj < 2; ++nj) {
    out[nj][0] = *(const bf16x8*)(s + (row0 + nj * 16) * BK + aoff0);
    out[nj][1] = *(const bf16x8*)(s + (row0 + nj * 16) * BK + aoff1);
  }
}

// 16 MFMAs of one quadrant (4 m-frags x 2 n-frags x K=64).
#define MFMA_Q(AF, BQ, MH, NH)                                                \
  _Pragma("unroll")                                                           \
  for (int ks = 0; ks < 2; ++ks)                                              \
    _Pragma("unroll")                                                         \
    for (int mi = 0; mi < 4; ++mi)                                            \
      _Pragma("unroll")                                                       \
      for (int nj = 0; nj < 2; ++nj)                                          \
        acc[(MH)*4 + mi][(NH)*2 + nj] =                                       \
            __builtin_amdgcn_mfma_f32_16x16x32_bf16(                          \
                AF[mi][ks], BQ[nj][ks], acc[(MH)*4 + mi][(NH)*2 + nj],        \
                0, 0, 0);

#define SBAR asm volatile("s_barrier" ::: "memory")
#define SCHEDB __builtin_amdgcn_sched_barrier(0)

// One K-tile = 4 phases. Fragment lifetimes (each loaded 1 phase early):
//   afA(t): loaded t-1.P3   bqA(t): loaded t-1.P4
//   bqB(t): loaded t.P1     afB(t): loaded t.P2
// Stage set S(t) = tile t+2 -> tile t's own buffers, issue order:
//   P1: A q0,q2 (p1-2)  P2: B q0,q1 (p3-4)  P3: A q1,q3 (p5-6)
//   P4: B q2,q3 (p7-8)   -- each placed right after its region's last read
//   (WAR fences: lgkmcnt(0) at P2-end and P4-end + barriers).
// RAW guards (outstanding-count verified, steady-state entry = 6 = S(t-1)
// p3-8): P3-begin vmcnt(10) [covers afA(t+1) = S(t-1) p1-2, first tile],
// P4-begin vmcnt(8) [bqA(t+1) = p3-4], P4-end vmcnt(6) [retires S(t-1)
// p5-8 (+p1-2 of S(t) in steady state) so t+1.P1/P2 reads are covered].
// Every drained load is >=3 phases (~1800 cy) old -> no stall.
#define KTILE(T, BF)                                                          \
  {                                                                           \
    const unsigned ko2 = (((T) + 2) & (KT - 1)) * BK;                         \
    const unsigned short* sa_ = sA[BF];                                       \
    const unsigned short* sb_ = sB[BF];                                       \
    const unsigned short* sa1 = sA[(BF) ^ 1];                                 \
    const unsigned short* sb1 = sB[(BF) ^ 1];                                 \
    unsigned short* waq = sA[BF] + (wave << 3) * BK;                          \
    unsigned short* wbq = sB[BF] + (wave << 3) * BK;                          \
    /* P1 (0,0): prefetch bqB(t); stage A q0,q2 */                            \
    load_b2(sb_, bnlo + 128, aoff0, aoff1, bqB);                              \
    stage2(A, waq + 0 * BK, aU + 0u * K_DIM + ko2 + laneoff);                 \
    stage2(A, waq + 128 * BK, aU + 128u * K_DIM + ko2 + laneoff);             \
    SCHEDB;                                                                   \
    __builtin_amdgcn_s_setprio(1);                                            \
    MFMA_Q(afA, bqA, 0, 0);                                                   \
    __builtin_amdgcn_s_setprio(0);                                            \
    SCHEDB;                                                                   \
    SBAR;                                                                     \
    /* P2 (0,1): prefetch afB(t); stage B q0,q1 */                            \
    load_a4(sa_, wm + 64, aoff0, aoff1, afB);                                 \
    stage2(B, wbq + 0 * BK, bU + 0u * K_DIM + ko2 + laneoff);                 \
    stage2(B, wbq + 64 * BK, bU + 64u * K_DIM + ko2 + laneoff);               \
    SCHEDB;                                                                   \
    __builtin_amdgcn_s_setprio(1);                                            \
    MFMA_Q(afA, bqB, 0, 1);                                                   \
    __builtin_amdgcn_s_setprio(0);                                            \
    SCHEDB;                                                                   \
    asm volatile("s_waitcnt lgkmcnt(0)" ::: "memory");                        \
    SBAR;                                                                     \
    /* P3 (1,0): vm guard; prefetch afA(t+1) [other buf]; stage A q1,q3 */    \
    asm volatile("s_waitcnt vmcnt(10)" ::: "memory");                         \
    load_a4(sa1, wm + 0, aoff0, aoff1, afA);                                  \
    stage2(A, waq + 64 * BK, aU + 64u * K_DIM + ko2 + laneoff);               \
    stage2(A, waq + 192 * BK, aU + 192u * K_DIM + ko2 + laneoff);             \
    SCHEDB;                                                                   \
    __builtin_amdgcn_s_setprio(1);                                            \
    MFMA_Q(afB, bqA, 1, 0);                                                   \
    __builtin_amdgcn_s_setprio(0);                                            \
    SCHEDB;                                                                   \
    SBAR;                                                                     \
    /* P4 (1,1): vm guard; prefetch bqA(t+1) [other buf]; stage B q2,q3 */    \
    asm volatile("s_waitcnt vmcnt(8)" ::: "memory");                          \
    load_b2(sb1, bnlo, aoff0, aoff1, bqA);                                    \
    stage2(B, wbq + 128 * BK, bU + 128u * K_DIM + ko2 + laneoff);             \
    stage2(B, wbq + 192 * BK, bU + 192u * K_DIM + ko2 + laneoff);             \
    SCHEDB;                                                                   \
    __builtin_amdgcn_s_setprio(1);                                            \
    MFMA_Q(afB, bqB, 1, 1);                                                   \
    __builtin_amdgcn_s_setprio(0);                                            \
    SCHEDB;                                                                   \
    asm volatile("s_waitcnt lgkmcnt(0)" ::: "memory");                        \
    asm volatile("s_waitcnt vmcnt(6)" ::: "memory");                          \
    SBAR;                                                                     \
  }

__global__ __launch_bounds__(512, 2) void gemm_bt(
    const unsigned short* __restrict__ A,
    const unsigned short* __restrict__ B,
    float* __restrict__ C) {
  __shared__ __align__(16) unsigned short sA[2][BM * BK];  // 64 KB
  __shared__ __align__(16) unsigned short sB[2][BN * BK];  // 64 KB

  const int tid = threadIdx.x;
  const int wave = tid >> 6;
  const int lane = tid & 63;

  // XCD swizzle: 256 blocks; XCD c owns m-tile c, n-tiles 0..31 -> the 4 MB
  // A panel is resident in that XCD's L2.
  const int bid = blockIdx.x;
  const int swz = (bid & 7) * 32 + (bid >> 3);
  const int m0 = (swz >> 5) * BM;
  const int n0 = (swz & 31) * BN;

  const int wm = (wave >> 2) * 128;  // 0 or 128 (M-half)
  const int bnlo = (wave & 3) * 32;  // B row base for nh=0 (nh=1: +128)

  // staging: per-lane invariant offset (1 VGPR) + uniform SGPR bases
  const int srow = lane >> 3;                // 0..7
  const int scol = ((lane & 7) ^ srow) * 8;  // swizzled k-chunk (elements)
  const unsigned laneoff = (unsigned)(srow * K_DIM + scol);
  const unsigned aU = (unsigned)((m0 + (wave << 3)) * K_DIM);
  const unsigned bU = (unsigned)((n0 + (wave << 3)) * K_DIM);

  // reader lane coords -> shared per-lane LDS element offsets
  const int rrow = lane & 15;
  const int rk = lane >> 4;  // 0..3
  const int aoff0 = rrow * BK + ((rk) ^ (rrow & 7)) * 8;
  const int aoff1 = rrow * BK + ((4 + rk) ^ (rrow & 7)) * 8;

  bf16x8 afA[4][2], afB[4][2];
  bf16x8 bqA[2][2], bqB[2][2];
  f32x4 acc[8][4];
#pragma unroll
  for (int m = 0; m < 8; ++m)
#pragma unroll
    for (int n = 0; n < 4; ++n)
#pragma unroll
      for (int r = 0; r < 4; ++r) acc[m][n][r] = 0.0f;

  // Prologue: S(-2)=tile0->buf0, S(-1)=tile1->buf1, both in canonical
  // p1..p8 order (positions matter for the vmcnt guards). vmcnt(8) drains
  // tile 0; initial afA(t0)/bqA(t0) reads; fence; enter loop.
  {
    unsigned short* pa0 = sA[0] + (wave << 3) * BK;
    unsigned short* pb0 = sB[0] + (wave << 3) * BK;
    unsigned short* pa1 = sA[1] + (wave << 3) * BK;
    unsigned short* pb1 = sB[1] + (wave << 3) * BK;
    stage2(A, pa0 + 0 * BK, aU + 0u * K_DIM + laneoff);
    stage2(A, pa0 + 128 * BK, aU + 128u * K_DIM + laneoff);
    stage2(B, pb0 + 0 * BK, bU + 0u * K_DIM + laneoff);
    stage2(B, pb0 + 64 * BK, bU + 64u * K_DIM + laneoff);
    stage2(A, pa0 + 64 * BK, aU + 64u * K_DIM + laneoff);
    stage2(A, pa0 + 192 * BK, aU + 192u * K_DIM + laneoff);
    stage2(B, pb0 + 128 * BK, bU + 128u * K_DIM + laneoff);
    stage2(B, pb0 + 192 * BK, bU + 192u * K_DIM + laneoff);
    stage2(A, pa1 + 0 * BK, aU + 0u * K_DIM + BK + laneoff);
    stage2(A, pa1 + 128 * BK, aU + 128u * K_DIM + BK + laneoff);
    stage2(B, pb1 + 0 * BK, bU + 0u * K_DIM + BK + laneoff);
    stage2(B, pb1 + 64 * BK, bU + 64u * K_DIM + BK + laneoff);
    stage2(A, pa1 + 64 * BK, aU + 64u * K_DIM + BK + laneoff);
    stage2(A, pa1 + 192 * BK, aU + 192u * K_DIM + BK + laneoff);
    stage2(B, pb1 + 128 * BK, bU + 128u * K_DIM + BK + laneoff);
    stage2(B, pb1 + 192 * BK, bU + 192u * K_DIM + BK + laneoff);
  }
  asm volatile("s_waitcnt vmcnt(8)" ::: "memory");
  SBAR;
  load_a4(sA[0], wm + 0, aoff0, aoff1, afA);
  load_b2(sB[0], bnlo, aoff0, aoff1, bqA);
  asm volatile("s_waitcnt lgkmcnt(0)" ::: "memory");
  SBAR;

#pragma unroll 1
  for (int tt = 0; tt < KT / 2; ++tt) {
    KTILE(2 * tt, 0)
    KTILE(2 * tt + 1, 1)
  }
  asm volatile("s_waitcnt vmcnt(0) lgkmcnt(0)" ::: "memory");

  // Epilogue: C/D layout col = lane&15, row = (lane>>4)*4 + reg.
  // Row for acc[m][.]: wm + m*16. Col for acc[.][n]: bnlo + (n>>1)*128 +
  // (n&1)*16.
  const int crow0 = m0 + wm + 4 * rk;
  const int ccol0 = n0 + bnlo + rrow;
#pragma unroll
  for (int m = 0; m < 8; ++m)
#pragma unroll
    for (int n = 0; n < 4; ++n)
#pragma unroll
      for (int r = 0; r < 4; ++r)
        C[(size_t)(crow0 + m * 16 + r) * N_DIM + ccol0 + (n >> 1) * 128 +
          (n & 1) * 16] = acc[m][n][r];
}

// Safety-net fallback (only if ws_size < 160 MB): correct fp32, slow.
__global__ void naive_kernel(const float* __restrict__ x,
                             const int* __restrict__ qw,
                             const float* __restrict__ lut,
                             float* __restrict__ out) {
  int o = blockIdx.x * blockDim.x + threadIdx.x;
  int s = blockIdx.y;
  const float* xr = x + (size_t)s * K_DIM;
  const unsigned int* qr = (const unsigned int*)qw + (size_t)o * (K_DIM / 4);
  const float* l = lut + o * 16;
  float acc = 0.f;
  for (int w = 0; w < K_DIM / 4; ++w) {
    unsigned int q = qr[w];
    acc += xr[w * 4 + 0] * l[(q >> 4) & 15u]
         + xr[w * 4 + 1] * l[(q >> 12) & 15u]
         + xr[w * 4 + 2] * l[(q >> 20) & 15u]
         + xr[w * 4 + 3] * l[(q >> 28) & 15u];
  }
  out[(size_t)s * N_DIM + o] = acc;
}

extern "C" void kernel_launch(void* const* d_in, const int* in_sizes, int n_in,
                              void* d_out, int out_size, void* d_ws,
                              size_t ws_size, hipStream_t stream) {
  const float* x = (const float*)d_in[0];
  const int* qw = (const int*)d_in[1];
  const float* lut = (const float*)d_in[2];
  float* out = (float*)d_out;

  const size_t wb_elems = (size_t)N_DIM * K_DIM;  // 128 MB bf16
  const size_t xb_elems = (size_t)M_DIM * K_DIM;  //  32 MB bf16
  const size_t need = (wb_elems + xb_elems) * sizeof(unsigned short);

  if (ws_size >= need) {
    unsigned short* wb = (unsigned short*)d_ws;
    unsigned short* xb = wb + wb_elems;

    hipLaunchKernelGGL(dequant_kernel, dim3(N_DIM / 4), dim3(256), 0, stream,
                       (const int4*)qw, lut, wb);

    const int n_thr = M_DIM * K_DIM / 8;  // 8 elem/thread
    hipLaunchKernelGGL(cvt_x_kernel, dim3(n_thr / 256), dim3(256), 0, stream,
                       (const float4*)x, (unsigned int*)xb);

    hipLaunchKernelGGL(gemm_bt, dim3((M_DIM / BM) * (N_DIM / BN)), dim3(512),
                       0, stream, xb, wb, out);
  } else {
    dim3 grid(N_DIM / 256, M_DIM);
    hipLaunchKernelGGL(naive_kernel, grid, dim3(256), 0, stream, x, qw, lut,
                       out);
  }
}

// Round 5
// 433.116 us; speedup vs baseline: 1.2362x; 1.0661x over previous
//
#include <hip/hip_runtime.h>
#include <stdint.h>

// AnyprecisionLinear: out[s,o] = sum_k x[s,k] * lut[o, code(o,k)>>4]
// M=2048, N=8192, K=8192. fp32 in/out, bf16 MFMA compute.
//
// R8: PIVOT — fuse dequant into the GEMM's B-staging.
//  - dequant_kernel deleted: B is dequantized in-loop from qweight + a
//    per-block LDS LUT (256 rows x 16 entries, stride 17 dwords to spread
//    banks; 17 coprime 32 -> 32 distinct base banks across a wave).
//    Eliminates 128 MB wb write + 128 MB re-read + ~130 us kernel time;
//    GEMM B-side HBM fetch shrinks 4x (qweight vs bf16 wb).
//  - GEMM schedule simplified to ONE barrier per K-tile (R5/R6/R7 showed the
//    multi-phase schedules plateau at ~40% MfmaUtil here): max wave drift so
//    one wave's gather/VALU overlaps another's MFMA. Hazard audit: all
//    read(iter u, buf u&1) vs write(iter u, buf ~u&1) pairs are cross-buffer;
//    cross-iteration pairs sealed by the barrier + lgkmcnt(0)/vmcnt(0)
//    (both waits hit loads/writes issued ~3000 cy earlier -> free).
//  - B stage: 2x global dwordx4/lane (t+1) issued at tile start, consumed
//    after the MFMA cluster (sched_barrier pins BDEQ late so the vmcnt wait
//    lands on ~3000-cy-old loads); 32 LUT gathers + pack + 4 ds_write_b128
//    at slot = chunk ^ (row&7) (same swizzle the reader uses; write banking
//    = even 8/bank floor, verified).
//  - A stage: unchanged global_load_lds quarters (lean SGPR+laneoff addr).

#define M_DIM 2048
#define N_DIM 8192
#define K_DIM 8192
#define BM 256
#define BN 256
#define BK 64
#define KT (K_DIM / BK)  // 128 K-tiles
#define LUTS 17          // LDS LUT row stride (dwords), coprime with 32

typedef __bf16 bf16x8 __attribute__((ext_vector_type(8)));
typedef float f32x4 __attribute__((ext_vector_type(4)));

__device__ __forceinline__ unsigned int f2bf(float f) {
  // round-to-nearest-even fp32 -> bf16
  unsigned int u = __float_as_uint(f);
  return (u + 0x7FFFu + ((u >> 16) & 1u)) >> 16;
}

// ---------------- x fp32 -> bf16, 8 elements/thread, 16 B stores -----------
__global__ __launch_bounds__(256) void cvt_x_kernel(
    const float4* __restrict__ x4, unsigned int* __restrict__ xb) {
  const int idx = blockIdx.x * 256 + threadIdx.x;
  float4 a = x4[2 * idx];
  float4 b = x4[2 * idx + 1];
  uint4 o;
  o.x = f2bf(a.x) | (f2bf(a.y) << 16);
  o.y = f2bf(a.z) | (f2bf(a.w) << 16);
  o.z = f2bf(b.x) | (f2bf(b.y) << 16);
  o.w = f2bf(b.z) | (f2bf(b.w) << 16);
  ((uint4*)xb)[idx] = o;
}

// ---------------- fused GEMM: C = A * dequant(qw)^T ------------------------
// LDS per buffer: [256 rows][64 cols] bf16; 16 B chunk-slot s of row r holds
// global k-chunk s ^ (r&7) (conflict-free for the 16x16x32 reader; R4-R7: 0).
// A/B operand (16x16x32): row/col = lane&15, k = (lane>>4)*8 + j.
// C/D: col = lane&15, row = (lane>>4)*4 + reg  [m89/m91].

__device__ __forceinline__ void stage2(const unsigned short* __restrict__ g,
                                       unsigned short* lds, unsigned off) {
  __builtin_amdgcn_global_load_lds(
      (const __attribute__((address_space(1))) void*)(g + off),
      (__attribute__((address_space(3))) void*)lds, 16, 0, 0);
}

__device__ __forceinline__ void load_a4(const unsigned short* __restrict__ s,
                                        int row0, int aoff0, int aoff1,
                                        bf16x8 out[4][2]) {
#pragma unroll
  for (int mi = 0; mi < 4; ++mi) {
    out[mi][0] = *(const bf16x8*)(s + (row0 + mi * 16) * BK + aoff0);
    out[mi][1] = *(const bf16x8*)(s + (row0 + mi * 16) * BK + aoff1);
  }
}

__device__ __forceinline__ void load_b2(const unsigned short* __restrict__ s,
                                        int row0, int aoff0, int aoff1,
                                        bf16x8 out[2][2]) {
#pragma unroll
  for (int nj = 0; nj < 2; ++nj) {
    out[nj][0] = *(const bf16x8*)(s + (row0 + nj * 16) * BK + aoff0);
    out[nj][1] = *(const bf16x8*)(s + (row0 + nj * 16) * BK + aoff1);
  }
}

// 16 MFMAs of one quadrant (4 m-frags x 2 n-frags x K=64).
#define MFMA_Q(AF, BQ, MH, NH)                                                \
  _Pragma("unroll")                                                           \
  for (int ks = 0; ks < 2; ++ks)                                              \
    _Pragma("unroll")                                                         \
    for (int mi = 0; mi < 4; ++mi)                                            \
      _Pragma("unroll")                                                       \
      for (int nj = 0; nj < 2; ++nj)                                          \
        acc[(MH)*4 + mi][(NH)*2 + nj] =                                       \
            __builtin_amdgcn_mfma_f32_16x16x32_bf16(                          \
                AF[mi][ks], BQ[nj][ks], acc[(MH)*4 + mi][(NH)*2 + nj],        \
                0, 0, 0);

#define SBAR asm volatile("s_barrier" ::: "memory")
#define SCHEDB __builtin_amdgcn_sched_barrier(0)

// Dequant one 16 B chunk: 8 codes from words W0,W1 -> 8 bf16 via LUT gather,
// packed and written at swizzled slot ((bkh*4+J)^bsw). idx = top 4 bits of
// each byte's 8-bit code -> always in [0,16): gathers are bounds-safe even
// on the wrapped tail tile's garbage words.
#define BCHUNK(W0, W1, J)                                                     \
  {                                                                           \
    unsigned v0 = slut_row[((W0) >> 4) & 15u];                                \
    unsigned v1 = slut_row[((W0) >> 12) & 15u];                               \
    unsigned v2 = slut_row[((W0) >> 20) & 15u];                               \
    unsigned v3 = slut_row[(W0) >> 28];                                       \
    unsigned v4 = slut_row[((W1) >> 4) & 15u];                                \
    unsigned v5 = slut_row[((W1) >> 12) & 15u];                               \
    unsigned v6 = slut_row[((W1) >> 20) & 15u];                               \
    unsigned v7 = slut_row[(W1) >> 28];                                       \
    uint4 o;                                                                  \
    o.x = v0 | (v1 << 16);                                                    \
    o.y = v2 | (v3 << 16);                                                    \
    o.z = v4 | (v5 << 16);                                                    \
    o.w = v6 | (v7 << 16);                                                    \
    *(uint4*)(bw + ((((bkh << 2) + (J)) ^ bsw) << 3)) = o;                    \
  }

#define BDEQ(Q0, Q1, BW)                                                      \
  {                                                                           \
    unsigned short* bw = BW;                                                  \
    BCHUNK((unsigned)(Q0).x, (unsigned)(Q0).y, 0)                             \
    BCHUNK((unsigned)(Q0).z, (unsigned)(Q0).w, 1)                             \
    BCHUNK((unsigned)(Q1).x, (unsigned)(Q1).y, 2)                             \
    BCHUNK((unsigned)(Q1).z, (unsigned)(Q1).w, 3)                             \
  }

// One K-tile, one barrier. Order: issue B q-loads(t+1) + A DMA(t+1) ->
// compute tile t (24 ds_read_b128 + 64 MFMA) -> BDEQ(t+1) (pinned after
// MFMA by SCHEDB; its vmcnt wait hits ~3000-cy-old loads) -> drain (old
// loads/writes, free) -> barrier.
#define FTILE(T, P)                                                           \
  {                                                                           \
    const unsigned ko1 = (((T) + 1) & (KT - 1)) * BK;                         \
    uint4 q0 = qwrow[ko1 >> 4];                                               \
    uint4 q1 = qwrow[(ko1 >> 4) + 1];                                         \
    unsigned short* nxtA = sA[(P) ^ 1] + (wave << 3) * BK;                    \
    stage2(A, nxtA + 0 * BK, aU + 0u * K_DIM + ko1 + laneoff);                \
    stage2(A, nxtA + 64 * BK, aU + 64u * K_DIM + ko1 + laneoff);              \
    stage2(A, nxtA + 128 * BK, aU + 128u * K_DIM + ko1 + laneoff);            \
    stage2(A, nxtA + 192 * BK, aU + 192u * K_DIM + ko1 + laneoff);            \
    const unsigned short* sa_ = sA[P];                                        \
    const unsigned short* sb_ = sB[P];                                        \
    load_b2(sb_, bnlo, aoff0, aoff1, bq0);                                    \
    load_b2(sb_, bnlo + 128, aoff0, aoff1, bq1);                              \
    load_a4(sa_, wm, aoff0, aoff1, af);                                       \
    __builtin_amdgcn_s_setprio(1);                                            \
    MFMA_Q(af, bq0, 0, 0);                                                    \
    MFMA_Q(af, bq1, 0, 1);                                                    \
    __builtin_amdgcn_s_setprio(0);                                            \
    load_a4(sa_, wm + 64, aoff0, aoff1, af);                                  \
    __builtin_amdgcn_s_setprio(1);                                            \
    MFMA_Q(af, bq0, 1, 0);                                                    \
    MFMA_Q(af, bq1, 1, 1);                                                    \
    __builtin_amdgcn_s_setprio(0);                                            \
    SCHEDB;                                                                   \
    BDEQ(q0, q1, sB[(P) ^ 1] + brow * BK)                                     \
    asm volatile("s_waitcnt vmcnt(0) lgkmcnt(0)" ::: "memory");               \
    SBAR;                                                                     \
  }

__global__ __launch_bounds__(512, 2) void gemm_fused(
    const unsigned short* __restrict__ A,
    const uint4* __restrict__ qw4,
    const float* __restrict__ lut,
    float* __restrict__ C) {
  __shared__ __align__(16) unsigned short sA[2][BM * BK];  // 64 KB
  __shared__ __align__(16) unsigned short sB[2][BN * BK];  // 64 KB
  __shared__ unsigned slut[256 * LUTS];                    // 17 KB

  const int tid = threadIdx.x;
  const int wave = tid >> 6;
  const int lane = tid & 63;

  // XCD swizzle: 256 blocks; XCD c owns m-tile c, n-tiles 0..31.
  const int bid = blockIdx.x;
  const int swz = (bid & 7) * 32 + (bid >> 3);
  const int m0 = (swz >> 5) * BM;
  const int n0 = (swz & 31) * BN;

  const int wm = (wave >> 2) * 128;  // 0 or 128 (M-half)
  const int bnlo = (wave & 3) * 32;  // B row base for nh=0 (nh=1: +128)

  // A staging: per-lane invariant offset + uniform base
  const int srow = lane >> 3;                // 0..7
  const int scol = ((lane & 7) ^ srow) * 8;  // swizzled k-chunk (elements)
  const unsigned laneoff = (unsigned)(srow * K_DIM + scol);
  const unsigned aU = (unsigned)((m0 + (wave << 3)) * K_DIM);

  // B dequant lane coords: lane pair (2i,2i+1) handles local row i of the
  // wave's 32-row strip; bkh selects the k-half (32 codes = 8 words = 2x16B).
  const int brow = (wave << 5) + (lane >> 1);  // 0..255 local B row
  const int bkh = lane & 1;
  const int bsw = brow & 7;
  const unsigned* slut_row = slut + brow * LUTS;
  const uint4* qwrow = qw4 + (size_t)(n0 + brow) * 512 + bkh * 2;

  // reader lane coords -> shared per-lane LDS element offsets
  const int rrow = lane & 15;
  const int rk = lane >> 4;  // 0..3
  const int aoff0 = rrow * BK + ((rk) ^ (rrow & 7)) * 8;
  const int aoff1 = rrow * BK + ((4 + rk) ^ (rrow & 7)) * 8;

  bf16x8 af[4][2];
  bf16x8 bq0[2][2], bq1[2][2];
  f32x4 acc[8][4];
#pragma unroll
  for (int m = 0; m < 8; ++m)
#pragma unroll
    for (int n = 0; n < 4; ++n)
#pragma unroll
      for (int r = 0; r < 4; ++r) acc[m][n][r] = 0.0f;

  // LUT init: thread covers (row tid>>1, entries (tid&1)*8..+8).
  {
    const float* lr = lut + (size_t)(n0 + (tid >> 1)) * 16 + (tid & 1) * 8;
    unsigned* dst = slut + (tid >> 1) * LUTS + (tid & 1) * 8;
#pragma unroll
    for (int e = 0; e < 8; ++e) dst[e] = f2bf(lr[e]);
  }

  // Prologue: stage tile 0 (A via DMA, B via load+gather after LUT barrier).
  uint4 p0 = qwrow[0];
  uint4 p1 = qwrow[1];
  {
    unsigned short* pa0 = sA[0] + (wave << 3) * BK;
    stage2(A, pa0 + 0 * BK, aU + 0u * K_DIM + laneoff);
    stage2(A, pa0 + 64 * BK, aU + 64u * K_DIM + laneoff);
    stage2(A, pa0 + 128 * BK, aU + 128u * K_DIM + laneoff);
    stage2(A, pa0 + 192 * BK, aU + 192u * K_DIM + laneoff);
  }
  __syncthreads();  // LUT writes visible to all gathers
  BDEQ(p0, p1, sB[0] + brow * BK)
  asm volatile("s_waitcnt vmcnt(0) lgkmcnt(0)" ::: "memory");
  SBAR;

#pragma unroll 1
  for (int tt = 0; tt < KT / 2; ++tt) {
    FTILE(2 * tt, 0)
    FTILE(2 * tt + 1, 1)
  }

  // Epilogue: C/D layout col = lane&15, row = (lane>>4)*4 + reg.
  // Row for acc[m][.]: wm + m*16. Col for acc[.][n]: bnlo + (n>>1)*128 +
  // (n&1)*16.
  const int crow0 = m0 + wm + 4 * rk;
  const int ccol0 = n0 + bnlo + rrow;
#pragma unroll
  for (int m = 0; m < 8; ++m)
#pragma unroll
    for (int n = 0; n < 4; ++n)
#pragma unroll
      for (int r = 0; r < 4; ++r)
        C[(size_t)(crow0 + m * 16 + r) * N_DIM + ccol0 + (n >> 1) * 128 +
          (n & 1) * 16] = acc[m][n][r];
}

// Safety-net fallback (only if workspace too small): correct fp32, slow.
__global__ void naive_kernel(const float* __restrict__ x,
                             const int* __restrict__ qw,
                             const float* __restrict__ lut,
                             float* __restrict__ out) {
  int o = blockIdx.x * blockDim.x + threadIdx.x;
  int s = blockIdx.y;
  const float* xr = x + (size_t)s * K_DIM;
  const unsigned int* qr = (const unsigned int*)qw + (size_t)o * (K_DIM / 4);
  const float* l = lut + o * 16;
  float acc = 0.f;
  for (int w = 0; w < K_DIM / 4; ++w) {
    unsigned int q = qr[w];
    acc += xr[w * 4 + 0] * l[(q >> 4) & 15u]
         + xr[w * 4 + 1] * l[(q >> 12) & 15u]
         + xr[w * 4 + 2] * l[(q >> 20) & 15u]
         + xr[w * 4 + 3] * l[(q >> 28) & 15u];
  }
  out[(size_t)s * N_DIM + o] = acc;
}

extern "C" void kernel_launch(void* const* d_in, const int* in_sizes, int n_in,
                              void* d_out, int out_size, void* d_ws,
                              size_t ws_size, hipStream_t stream) {
  const float* x = (const float*)d_in[0];
  const int* qw = (const int*)d_in[1];
  const float* lut = (const float*)d_in[2];
  float* out = (float*)d_out;

  const size_t xb_elems = (size_t)M_DIM * K_DIM;  // 32 MB bf16
  const size_t need = xb_elems * sizeof(unsigned short);

  if (ws_size >= need) {
    unsigned short* xb = (unsigned short*)d_ws;

    const int n_thr = M_DIM * K_DIM / 8;  // 8 elem/thread
    hipLaunchKernelGGL(cvt_x_kernel, dim3(n_thr / 256), dim3(256), 0, stream,
                       (const float4*)x, (unsigned int*)xb);

    hipLaunchKernelGGL(gemm_fused, dim3((M_DIM / BM) * (N_DIM / BN)),
                       dim3(512), 0, stream, xb, (const uint4*)qw, lut, out);
  } else {
    dim3 grid(N_DIM / 256, M_DIM);
    hipLaunchKernelGGL(naive_kernel, grid, dim3(256), 0, stream, x, qw, lut,
                       out);
  }
}